// Round 9
// baseline (33.943 us; speedup 1.0000x reference)
//
#include <hip/hip_runtime.h>
#include <hip/hip_bf16.h>

// WordPooling: hidden_states [B,S,H] fp32, segment_ids [B*S] sorted int32,
// output pooled [num_words, H] fp32 (mean per contiguous word segment;
// empty words -> zeros).
//
// Round-9: search-count reduction, stage 2 (r8's -1.1us proved searches cost
// ~0.18us per 1000 wave-searches).
//  - Each wave owns 4 CONSECUTIVE words; interior boundaries found by reading
//    seg[t] (wave-uniform, L2-hot) during the stream -- no searches for them.
//  - Block = 4 waves = 16 words; 5 shared wave-parallel searches per block
//    (start of each wave's group + block end) -> 2560 searches total vs 10240.
//  - 512 blocks x 256 threads = 2048 waves (8/CU): in-flight arithmetic says
//    8 waves x 4KB >> 9KB/CU needed to cover HBM latency.

__device__ __forceinline__ int wave_lower_bound(const int* __restrict__ seg,
                                                int n, int val, int lane) {
    int lo = 0;
    int len = n;
    while (len > 64) {
        const int stride = (len + 63) >> 6;          // ceil(len/64)
        const int idx = lo + lane * stride;
        const int v = (idx < n) ? seg[idx] : 0x7fffffff;
        const unsigned long long m = __ballot(v < val);
        const int cnt = __popcll(m);                 // prefix count (seg sorted)
        if (cnt > 0) lo += (cnt - 1) * stride + 1;   // lb in (p[cnt-1], p[cnt]]
        len = stride;
    }
    {
        const int idx = lo + lane;
        const int v = (idx < n) ? seg[idx] : 0x7fffffff;
        const unsigned long long m = __ballot(v < val);
        lo += __popcll(m);
    }
    return lo;
}

__global__ __launch_bounds__(256)
void word_pool_kernel(const float* __restrict__ hs,
                      const int* __restrict__ seg,
                      float* __restrict__ out,
                      int n_tokens, int H, int n_words) {
    __shared__ int bounds[5];

    const int wave = threadIdx.x >> 6;     // 0..3
    const int lane = threadIdx.x & 63;
    const int wb0 = blockIdx.x * 16;       // first word of block
    const int w0  = wb0 + wave * 4;        // first word of this wave's group

    // Wave i computes start(wb0 + 4i); wave 3 also start(wb0 + 16).
    const int start = wave_lower_bound(seg, n_tokens, w0, lane);
    if (lane == 0) bounds[wave] = start;
    if (wave == 3) {
        const int b4 = wave_lower_bound(seg, n_tokens, wb0 + 16, lane);
        if (lane == 0) bounds[4] = b4;
    }
    __syncthreads();
    const int end = bounds[wave + 1];      // end of this wave's 4-word group

    // H = 1024 = 64 lanes * 4 chunks * 4 floats.
    const int c0 = lane * 4;               // chunk j at column c0 + j*256

    float4 acc0 = make_float4(0.f, 0.f, 0.f, 0.f);
    float4 acc1 = acc0, acc2 = acc0, acc3 = acc0;
    int cur = w0;                          // word currently being accumulated
    int cnt = 0;

    for (int t = start; t < end; ++t) {
        // Row load first (address independent of seg[t]; pipelines ahead).
        const float* row = hs + (size_t)t * H + c0;
        const float4 v0 = *reinterpret_cast<const float4*>(row);
        const float4 v1 = *reinterpret_cast<const float4*>(row + 256);
        const float4 v2 = *reinterpret_cast<const float4*>(row + 512);
        const float4 v3 = *reinterpret_cast<const float4*>(row + 768);

        const int s = seg[t];              // wave-uniform, L2-hot
        if (s != cur) {
            // Flush word `cur`, zeros for skipped (empty) words in (cur, s).
            const float inv = (cnt > 0) ? (1.0f / (float)cnt) : 0.0f;
            float* orow = out + (size_t)cur * H + c0;
            float4 o0 = acc0, o1 = acc1, o2 = acc2, o3 = acc3;
            o0.x *= inv; o0.y *= inv; o0.z *= inv; o0.w *= inv;
            o1.x *= inv; o1.y *= inv; o1.z *= inv; o1.w *= inv;
            o2.x *= inv; o2.y *= inv; o2.z *= inv; o2.w *= inv;
            o3.x *= inv; o3.y *= inv; o3.z *= inv; o3.w *= inv;
            *reinterpret_cast<float4*>(orow)       = o0;
            *reinterpret_cast<float4*>(orow + 256) = o1;
            *reinterpret_cast<float4*>(orow + 512) = o2;
            *reinterpret_cast<float4*>(orow + 768) = o3;
            const float4 z = make_float4(0.f, 0.f, 0.f, 0.f);
            for (int w = cur + 1; w < s; ++w) {
                float* zrow = out + (size_t)w * H + c0;
                *reinterpret_cast<float4*>(zrow)       = z;
                *reinterpret_cast<float4*>(zrow + 256) = z;
                *reinterpret_cast<float4*>(zrow + 512) = z;
                *reinterpret_cast<float4*>(zrow + 768) = z;
            }
            acc0 = z; acc1 = z; acc2 = z; acc3 = z;
            cnt = 0;
            cur = s;
        }

        acc0.x += v0.x; acc0.y += v0.y; acc0.z += v0.z; acc0.w += v0.w;
        acc1.x += v1.x; acc1.y += v1.y; acc1.z += v1.z; acc1.w += v1.w;
        acc2.x += v2.x; acc2.y += v2.y; acc2.z += v2.z; acc2.w += v2.w;
        acc3.x += v3.x; acc3.y += v3.y; acc3.z += v3.z; acc3.w += v3.w;
        ++cnt;
    }

    // Final flush: word `cur` plus zeros through w0+3.
    {
        const float inv = (cnt > 0) ? (1.0f / (float)cnt) : 0.0f;
        float* orow = out + (size_t)cur * H + c0;
        acc0.x *= inv; acc0.y *= inv; acc0.z *= inv; acc0.w *= inv;
        acc1.x *= inv; acc1.y *= inv; acc1.z *= inv; acc1.w *= inv;
        acc2.x *= inv; acc2.y *= inv; acc2.z *= inv; acc2.w *= inv;
        acc3.x *= inv; acc3.y *= inv; acc3.z *= inv; acc3.w *= inv;
        *reinterpret_cast<float4*>(orow)       = acc0;
        *reinterpret_cast<float4*>(orow + 256) = acc1;
        *reinterpret_cast<float4*>(orow + 512) = acc2;
        *reinterpret_cast<float4*>(orow + 768) = acc3;
        const float4 z = make_float4(0.f, 0.f, 0.f, 0.f);
        for (int w = cur + 1; w < w0 + 4; ++w) {
            float* zrow = out + (size_t)w * H + c0;
            *reinterpret_cast<float4*>(zrow)       = z;
            *reinterpret_cast<float4*>(zrow + 256) = z;
            *reinterpret_cast<float4*>(zrow + 512) = z;
            *reinterpret_cast<float4*>(zrow + 768) = z;
        }
    }
}

extern "C" void kernel_launch(void* const* d_in, const int* in_sizes, int n_in,
                              void* d_out, int out_size, void* d_ws, size_t ws_size,
                              hipStream_t stream) {
    const float* hs  = (const float*)d_in[0];   // [B*S, H] flattened
    const int*   seg = (const int*)d_in[1];     // [B*S], sorted
    float* out = (float*)d_out;

    const int n_tokens = in_sizes[1];              // B*S = 32768
    const int H        = in_sizes[0] / n_tokens;   // 1024
    const int n_words  = out_size / H;             // 8192

    dim3 grid(n_words / 16);                       // 16 words per block
    dim3 block(256);
    word_pool_kernel<<<grid, block, 0, stream>>>(hs, seg, out, n_tokens, H, n_words);
}

// Round 10
// 33.587 us; speedup vs baseline: 1.0106x; 1.0106x over previous
//
#include <hip/hip_runtime.h>
#include <hip/hip_bf16.h>

// WordPooling: hidden_states [B,S,H] fp32, segment_ids [B*S] sorted int32,
// output pooled [num_words, H] fp32 (mean per contiguous word segment;
// empty words -> zeros).
//
// FINAL (= round-8, best at 33.59 us): one wave per word, 4x float4 per lane,
// LDS-shared wave-parallel bounds (5 searches per 4-word block).
// Falsified levers (rounds 2-9): boundary-table precompute (+1.1us),
// 4x load ILP (0), oversubscription/imbalance (0 to -2.2us), nontemporal
// hints (-2us, forfeits L3 residency across graph replays), deeper
// search-count reduction via consecutive-word streaming (0, costs occupancy).
// Residual vs 27us copy-roofline: mixed-stream memory efficiency + ~2us
// dispatch overhead.

__device__ __forceinline__ int wave_lower_bound(const int* __restrict__ seg,
                                                int n, int val, int lane) {
    int lo = 0;
    int len = n;
    while (len > 64) {
        const int stride = (len + 63) >> 6;          // ceil(len/64)
        const int idx = lo + lane * stride;
        const int v = (idx < n) ? seg[idx] : 0x7fffffff;
        const unsigned long long m = __ballot(v < val);
        const int cnt = __popcll(m);                 // prefix count (seg sorted)
        if (cnt > 0) lo += (cnt - 1) * stride + 1;   // lb in (p[cnt-1], p[cnt]]
        len = stride;
    }
    {
        const int idx = lo + lane;
        const int v = (idx < n) ? seg[idx] : 0x7fffffff;
        const unsigned long long m = __ballot(v < val);
        lo += __popcll(m);
    }
    return lo;
}

__global__ __launch_bounds__(256)
void word_pool_kernel(const float* __restrict__ hs,
                      const int* __restrict__ seg,
                      float* __restrict__ out,
                      int n_tokens, int H, int n_words) {
    __shared__ int bounds[5];

    const int wave = threadIdx.x >> 6;     // 0..3
    const int lane = threadIdx.x & 63;
    const int w0 = blockIdx.x * 4;
    const int w  = w0 + wave;
    if (w >= n_words) return;

    // Wave i computes start(w0+i); wave 3 also start(w0+4). end(w) = start(w+1).
    const int start = wave_lower_bound(seg, n_tokens, w, lane);
    if (lane == 0) bounds[wave] = start;
    if (wave == 3) {
        const int b4 = wave_lower_bound(seg, n_tokens, w0 + 4, lane);
        if (lane == 0) bounds[4] = b4;
    }
    __syncthreads();
    const int end = bounds[wave + 1];

    // H = 1024 = 64 lanes * 4 chunks * 4 floats.
    const int c0 = lane * 4;               // chunk j at column c0 + j*256

    float4 acc0 = make_float4(0.f, 0.f, 0.f, 0.f);
    float4 acc1 = acc0, acc2 = acc0, acc3 = acc0;

    for (int t = start; t < end; ++t) {
        const float* row = hs + (size_t)t * H + c0;
        const float4 v0 = *reinterpret_cast<const float4*>(row);
        const float4 v1 = *reinterpret_cast<const float4*>(row + 256);
        const float4 v2 = *reinterpret_cast<const float4*>(row + 512);
        const float4 v3 = *reinterpret_cast<const float4*>(row + 768);
        acc0.x += v0.x; acc0.y += v0.y; acc0.z += v0.z; acc0.w += v0.w;
        acc1.x += v1.x; acc1.y += v1.y; acc1.z += v1.z; acc1.w += v1.w;
        acc2.x += v2.x; acc2.y += v2.y; acc2.z += v2.z; acc2.w += v2.w;
        acc3.x += v3.x; acc3.y += v3.y; acc3.z += v3.z; acc3.w += v3.w;
    }

    const int cnt = end - start;
    const float inv = (cnt > 0) ? (1.0f / (float)cnt) : 0.0f;
    acc0.x *= inv; acc0.y *= inv; acc0.z *= inv; acc0.w *= inv;
    acc1.x *= inv; acc1.y *= inv; acc1.z *= inv; acc1.w *= inv;
    acc2.x *= inv; acc2.y *= inv; acc2.z *= inv; acc2.w *= inv;
    acc3.x *= inv; acc3.y *= inv; acc3.z *= inv; acc3.w *= inv;

    float* orow = out + (size_t)w * H + c0;
    *reinterpret_cast<float4*>(orow)       = acc0;
    *reinterpret_cast<float4*>(orow + 256) = acc1;
    *reinterpret_cast<float4*>(orow + 512) = acc2;
    *reinterpret_cast<float4*>(orow + 768) = acc3;
}

extern "C" void kernel_launch(void* const* d_in, const int* in_sizes, int n_in,
                              void* d_out, int out_size, void* d_ws, size_t ws_size,
                              hipStream_t stream) {
    const float* hs  = (const float*)d_in[0];   // [B*S, H] flattened
    const int*   seg = (const int*)d_in[1];     // [B*S], sorted
    float* out = (float*)d_out;

    const int n_tokens = in_sizes[1];              // B*S = 32768
    const int H        = in_sizes[0] / n_tokens;   // 1024
    const int n_words  = out_size / H;             // 8192

    dim3 grid((n_words + 3) / 4);
    dim3 block(256);
    word_pool_kernel<<<grid, block, 0, stream>>>(hs, seg, out, n_tokens, H, n_words);
}